// Round 16
// baseline (249.790 us; speedup 1.0000x reference)
//
#include <hip/hip_runtime.h>
#include <hip/hip_bf16.h>
#include <type_traits>

#define D_MODEL 1024
#define N_HEADS 16
#define HEAD_DIM 64
#define SEQ 2048
#define BATCH 2
#define INNER_DIM 4096
#define ROWS (BATCH*SEQ)   // 4096

using f32x4  = __attribute__((ext_vector_type(4))) float;
using bf16x8 = __attribute__((ext_vector_type(8))) short;   // 8 bf16 raw bits

__device__ __forceinline__ void gl_lds16(const void* g, void* l) {
  __builtin_amdgcn_global_load_lds(
      (const __attribute__((address_space(1))) void*)g,
      (__attribute__((address_space(3))) void*)l, 16, 0, 0);
}

__device__ __forceinline__ float bf2f(unsigned short u) {
  union { unsigned int i; float f; } v; v.i = ((unsigned int)u) << 16; return v.f;
}
__device__ __forceinline__ unsigned short f2bf(float f) {
  union { float f; unsigned int i; } v; v.f = f;
  unsigned int x = v.i;
  return (unsigned short)((x + 0x7fffu + ((x >> 16) & 1u)) >> 16);  // RTNE
}

__device__ __forceinline__ float exp2fast(float x) {
  return __builtin_amdgcn_exp2f(x);
}

__device__ __forceinline__ float gelu_tanh(float x) {
  float x3 = x * x * x;
  float z = 0.7978845608028654f * (x + 0.044715f * x3);
  z = fminf(z, 15.0f);
  float e = __expf(2.0f * z);
  float th = (e - 1.0f) / (e + 1.0f);
  return 0.5f * x * (1.0f + th);
}

// ---------------- fused weight convert+transpose (all 4 weights, 1 launch) ----
__global__ void transpose_all(const float* __restrict__ w0, const float* __restrict__ w1,
                              const float* __restrict__ w2, const float* __restrict__ w3,
                              unsigned short* __restrict__ o0, unsigned short* __restrict__ o1,
                              unsigned short* __restrict__ o2, unsigned short* __restrict__ o3) {
  __shared__ float tile[32][33];
  int bid = blockIdx.x;
  const float* in; unsigned short* out; int K, N, nx;
  if (bid < 3072)      { in = w0; out = o0; K = 1024; N = 3072; nx = 96; }
  else if (bid < 4096) { in = w1; out = o1; K = 1024; N = 1024; nx = 32; bid -= 3072; }
  else if (bid < 8192) { in = w2; out = o2; K = 1024; N = 4096; nx = 128; bid -= 4096; }
  else                 { in = w3; out = o3; K = 4096; N = 1024; nx = 32; bid -= 8192; }
  int n0 = (bid % nx) * 32, k0 = (bid / nx) * 32;
  int tx = threadIdx.x, ty = threadIdx.y;   // 32 x 8
#pragma unroll
  for (int i = 0; i < 4; i++)
    tile[ty + i * 8][tx] = in[(size_t)(k0 + ty + i * 8) * N + n0 + tx];
  __syncthreads();
#pragma unroll
  for (int i = 0; i < 4; i++)
    out[(size_t)(n0 + ty + i * 8) * K + k0 + tx] = f2bf(tile[tx][ty + i * 8]);
}

// ---------------- LayerNorm + adaLN modulation -> bf16 ------------------------
template<int SH_IDX, int SC_IDX>
__global__ void ln_mod_kernel(const float* __restrict__ x,
                              const float* __restrict__ lw,
                              const float* __restrict__ lb,
                              const float* __restrict__ sst,
                              const float* __restrict__ temb,
                              unsigned short* __restrict__ out) {
  int row = blockIdx.x;
  int b = row >> 11;
  int t = threadIdx.x;
  const float* xr = x + (size_t)row * D_MODEL;
  float4 v = ((const float4*)xr)[t];
  float s = v.x + v.y + v.z + v.w;
  float s2 = v.x * v.x + v.y * v.y + v.z * v.z + v.w * v.w;
#pragma unroll
  for (int o = 1; o < 64; o <<= 1) { s += __shfl_xor(s, o); s2 += __shfl_xor(s2, o); }
  __shared__ float red[8];
  int wid = t >> 6, lane = t & 63;
  if (lane == 0) { red[wid] = s; red[4 + wid] = s2; }
  __syncthreads();
  s = red[0] + red[1] + red[2] + red[3];
  s2 = red[4] + red[5] + red[6] + red[7];
  float mu = s * (1.0f / D_MODEL);
  float var = s2 * (1.0f / D_MODEL) - mu * mu;
  float rs = rsqrtf(var + 1e-5f);
  int d0 = t * 4;
  float xv[4] = { v.x, v.y, v.z, v.w };
  ushort4 ov;
  unsigned short* po = (unsigned short*)&ov;
#pragma unroll
  for (int j = 0; j < 4; j++) {
    int d = d0 + j;
    float ln = (xv[j] - mu) * rs * lw[d] + lb[d];
    float sc = sst[SC_IDX * D_MODEL + d] + temb[b * 6 * D_MODEL + SC_IDX * D_MODEL + d];
    float sh = sst[SH_IDX * D_MODEL + d] + temb[b * 6 * D_MODEL + SH_IDX * D_MODEL + d];
    po[j] = f2bf(ln * (1.0f + sc) + sh);
  }
  *((ushort4*)(out + (size_t)row * D_MODEL + d0)) = ov;
}

// ---------------- GEMM (2-phase counted-vmcnt, R11 structure) -----------------
enum { EPI_QKV = 0, EPI_GELU = 2, EPI_PART = 3 };

template<int EPI, int NK>
__global__ __launch_bounds__(256, 2)
void gemm64(const unsigned short* __restrict__ A,
            const unsigned short* __restrict__ Bt,
            const float* __restrict__ bias,
            void* C0, void* C1,
            int N, int Kstride,
            const float* __restrict__ cosb,
            const float* __restrict__ sinb) {
  __shared__ unsigned short Alds[2][128 * 64];
  __shared__ unsigned short Blds[2][128 * 64];
  const int t = threadIdx.x;
  const int w = t >> 6, l = t & 63;
  const int lg = l >> 4, ll = l & 15;
  const int wm = w >> 1, wn = w & 1;
  const int kbase = blockIdx.z * (NK * 64);

  const int nx = gridDim.x;
  const int nwg = nx * gridDim.y;
  const int lid = blockIdx.y * nx + blockIdx.x;
  const int nid = (lid & 7) * (nwg >> 3) + (lid >> 3);
  const int m0 = (nid / nx) * 128, n0 = (nid % nx) * 128;

  void* Cout = blockIdx.z ? C1 : C0;

  f32x4 acc[4][4] = {};

  const unsigned short* ga[4];
  const unsigned short* gb[4];
#pragma unroll
  for (int i = 0; i < 4; i++) {
    int c = i * 256 + t, row = c >> 3, q = c & 7;
    ga[i] = A + (size_t)(m0 + row) * Kstride + kbase + ((q ^ (row & 7)) << 3);
    gb[i] = Bt + (size_t)(n0 + row) * Kstride + kbase + ((q ^ (row & 7)) << 3);
  }
  const unsigned short* ra[4][2];
  const unsigned short* rb[4][2];
#pragma unroll
  for (int f = 0; f < 4; f++) {
    int rowA = wm * 64 + f * 16 + ll;
    int rowB = wn * 64 + f * 16 + ll;
#pragma unroll
    for (int kk = 0; kk < 2; kk++) {
      ra[f][kk] = &Alds[0][rowA * 64 + ((((kk * 4 + lg) ^ (rowA & 7))) << 3)];
      rb[f][kk] = &Blds[0][rowB * 64 + ((((kk * 4 + lg) ^ (rowB & 7))) << 3)];
    }
  }

#pragma unroll
  for (int i = 0; i < 4; i++) {
    gl_lds16(ga[i], (char*)&Alds[0][0] + (i * 256 + t) * 16); ga[i] += 64;
  }
#pragma unroll
  for (int i = 0; i < 4; i++) {
    gl_lds16(gb[i], (char*)&Blds[0][0] + (i * 256 + t) * 16); gb[i] += 64;
  }

  auto giter = [&](auto BUFC, bool last) {
    constexpr int BUF = decltype(BUFC)::value;
    constexpr int NBUF = BUF ^ 1;
    if (!last) {
#pragma unroll
      for (int i = 0; i < 4; i++) {
        gl_lds16(ga[i], (char*)&Alds[NBUF][0] + (i * 256 + t) * 16); ga[i] += 64;
      }
#pragma unroll
      for (int i = 0; i < 4; i++) {
        gl_lds16(gb[i], (char*)&Blds[NBUF][0] + (i * 256 + t) * 16); gb[i] += 64;
      }
      asm volatile("s_waitcnt vmcnt(8)" ::: "memory");
    } else {
      asm volatile("s_waitcnt vmcnt(0)" ::: "memory");
    }
    __builtin_amdgcn_s_barrier();
    asm volatile("" ::: "memory");
#pragma unroll
    for (int kk = 0; kk < 2; kk++) {
      bf16x8 af[4], bfr[4];
#pragma unroll
      for (int mf = 0; mf < 4; mf++)
        af[mf] = *(const bf16x8*)(ra[mf][kk] + BUF * 8192);
#pragma unroll
      for (int nf = 0; nf < 4; nf++)
        bfr[nf] = *(const bf16x8*)(rb[nf][kk] + BUF * 8192);
#pragma unroll
      for (int mf = 0; mf < 4; mf++)
#pragma unroll
        for (int nf = 0; nf < 4; nf++)
          acc[mf][nf] = __builtin_amdgcn_mfma_f32_16x16x32_bf16(af[mf], bfr[nf], acc[mf][nf], 0, 0, 0);
    }
    asm volatile("" ::: "memory");
    __builtin_amdgcn_s_barrier();
  };

#pragma unroll 1
  for (int u = 0; u < NK - 2; u += 2) {
    giter(std::integral_constant<int, 0>{}, false);
    giter(std::integral_constant<int, 1>{}, false);
  }
  giter(std::integral_constant<int, 0>{}, false);
  giter(std::integral_constant<int, 1>{}, true);

#pragma unroll
  for (int mf = 0; mf < 4; mf++) {
#pragma unroll
    for (int nf = 0; nf < 4; nf++) {
      int col = n0 + wn * 64 + nf * 16 + ll;
      float bv = (EPI == EPI_PART) ? 0.0f : bias[col];
#pragma unroll
      for (int r = 0; r < 4; r++) {
        int row = m0 + wm * 64 + mf * 16 + lg * 4 + r;
        float v = acc[mf][nf][r] + bv;
        if constexpr (EPI == EPI_QKV) {
          if (col < 2048) {          // rope on q,k; pair = adjacent lane
            float vp = __shfl_xor(v, 1);
            int sp = row & (SEQ - 1);
            int ip = (col & 63) >> 1;
            float cz = cosb[sp * 32 + ip], sz = sinb[sp * 32 + ip];
            float ov = (col & 1) ? (vp * sz + v * cz) : (v * cz - vp * sz);
            if (col < 1024) ov *= 0.18033688011112042f;   // 0.125*log2e on Q
            v = ov;
          }
          ((unsigned short*)Cout)[(size_t)row * N + col] = f2bf(v);
        } else if constexpr (EPI == EPI_GELU) {
          ((unsigned short*)Cout)[(size_t)row * N + col] = f2bf(gelu_tanh(v));
        } else {   // EPI_PART: raw bf16 partial
          ((unsigned short*)Cout)[(size_t)row * N + col] = f2bf(v);
        }
      }
    }
  }
}

// ---------------- fused: hidden = (p0+p1+b)*g2 + resid; hln = LN2(hidden) -----
__global__ void reduce_ln(const unsigned short* __restrict__ p0,
                          const unsigned short* __restrict__ p1,
                          const float* __restrict__ bias,
                          const float* __restrict__ sst,
                          const float* __restrict__ temb,
                          const float* __restrict__ resid,
                          float* __restrict__ hidden,
                          const float* __restrict__ lw,
                          const float* __restrict__ lb,
                          unsigned short* __restrict__ hln) {
  int row = blockIdx.x, b = row >> 11, t = threadIdx.x;
  size_t base = (size_t)row * D_MODEL + t * 4;
  int col = t * 4;
  ushort4 a0 = *(const ushort4*)(p0 + base);
  ushort4 a1 = *(const ushort4*)(p1 + base);
  float4 rv = *(const float4*)(resid + base);
  const unsigned short* s0 = (const unsigned short*)&a0;
  const unsigned short* s1 = (const unsigned short*)&a1;
  const float* pr = (const float*)&rv;
  float h[4];
  float s = 0.0f, s2 = 0.0f;
#pragma unroll
  for (int j = 0; j < 4; j++) {
    int d = col + j;
    float g = sst[2 * D_MODEL + d] + temb[b * 6 * D_MODEL + 2 * D_MODEL + d];
    float v = (bf2f(s0[j]) + bf2f(s1[j]) + bias[d]) * g + pr[j];
    h[j] = v; s += v; s2 += v * v;
  }
  float4 hv; hv.x = h[0]; hv.y = h[1]; hv.z = h[2]; hv.w = h[3];
  *(float4*)(hidden + base) = hv;
#pragma unroll
  for (int o = 1; o < 64; o <<= 1) { s += __shfl_xor(s, o); s2 += __shfl_xor(s2, o); }
  __shared__ float red[8];
  int wid = t >> 6, lane = t & 63;
  if (lane == 0) { red[wid] = s; red[4 + wid] = s2; }
  __syncthreads();
  s = red[0] + red[1] + red[2] + red[3];
  s2 = red[4] + red[5] + red[6] + red[7];
  float mu = s * (1.0f / D_MODEL);
  float var = s2 * (1.0f / D_MODEL) - mu * mu;
  float rs = rsqrtf(var + 1e-5f);
  ushort4 ov;
  unsigned short* po = (unsigned short*)&ov;
#pragma unroll
  for (int j = 0; j < 4; j++) {
    int d = col + j;
    float ln = (h[j] - mu) * rs * lw[d] + lb[d];
    float sc = sst[4 * D_MODEL + d] + temb[b * 6 * D_MODEL + 4 * D_MODEL + d];
    float sh = sst[3 * D_MODEL + d] + temb[b * 6 * D_MODEL + 3 * D_MODEL + d];
    po[j] = f2bf(ln * (1.0f + sc) + sh);
  }
  *(ushort4*)(hln + base) = ov;
}

// ---------------- reduce: out_f32 = (p0+p1+bias)*g + resid --------------------
__global__ void reduce_gated(const unsigned short* __restrict__ p0,
                             const unsigned short* __restrict__ p1,
                             const float* __restrict__ bias,
                             const float* __restrict__ sst,
                             const float* __restrict__ temb,
                             int g_idx,
                             const float* __restrict__ resid,
                             float* __restrict__ out) {
  int i = blockIdx.x * 256 + threadIdx.x;
  int idx = i * 4;
  int col = idx & 1023;
  int b = idx >> 21;
  ushort4 a0 = *(const ushort4*)(p0 + idx);
  ushort4 a1 = *(const ushort4*)(p1 + idx);
  float4 rv = *(const float4*)(resid + idx);
  float4 o;
  const unsigned short* s0 = (const unsigned short*)&a0;
  const unsigned short* s1 = (const unsigned short*)&a1;
  float* po = (float*)&o;
  const float* pr = (const float*)&rv;
#pragma unroll
  for (int j = 0; j < 4; j++) {
    float s = bf2f(s0[j]) + bf2f(s1[j]) + bias[col + j];
    float g = sst[g_idx * D_MODEL + col + j] + temb[b * 6 * D_MODEL + g_idx * D_MODEL + col + j];
    po[j] = s * g + pr[j];
  }
  *(float4*)(out + idx) = o;
}

// ---------------- Flash attention (causal), swapped-operand softmax -----------
// 24KB LDS, ~48 VGPR -> request 6 blocks/CU (6 waves/SIMD) for latency hiding.
__global__ __launch_bounds__(256, 6)
void attn_kernel(const unsigned short* __restrict__ qkv,
                 unsigned short* __restrict__ attn_o) {
  __shared__ unsigned short Klds[2][64 * 64];
  __shared__ unsigned short Vt[2][64 * 64];
  __shared__ unsigned short Plds[4][16 * 64];

  const int id = blockIdx.x;
  const int bh = id & 31;
  const int b = bh >> 4, h = bh & 15;
  const int q0 = (31 - (id >> 5)) * 64;   // longest blocks first
  const int t = threadIdx.x;
  const int w = t >> 6, l = t & 63;
  const int lg = l >> 4, ll = l & 15;
  const int qw0 = q0 + w * 16;
  const int q_lane = qw0 + ll;

  bf16x8 qf[2];
  {
    const unsigned short* qb = qkv + (size_t)(b * SEQ + q_lane) * 3072 + h * 64;
    qf[0] = *(const bf16x8*)(qb + lg * 8);
    qf[1] = *(const bf16x8*)(qb + 32 + lg * 8);
  }

  const int kp = t & 31, dg = t >> 5;

  f32x4 oacc[4] = {};
  float mrun = -1e30f, lrun = 0.0f;

  {
#pragma unroll
    for (int i = 0; i < 2; i++) {
      int c = i * 256 + t;
      int kr = c >> 3, cc = c & 7;
      gl_lds16(qkv + (size_t)(b * SEQ + kr) * 3072 + 1024 + h * 64 + (cc ^ (kr & 7)) * 8,
               (char*)&Klds[0][0] + c * 16);
    }
    const unsigned short* vp = qkv + (size_t)(b * SEQ + 2 * kp) * 3072 + 2048 + h * 64 + dg * 8;
    union { uint4 u; unsigned short s[8]; } a0, a1;
    a0.u = *(const uint4*)vp;
    a1.u = *(const uint4*)(vp + 3072);
    unsigned int* vt32 = (unsigned int*)&Vt[0][0];
#pragma unroll
    for (int i = 0; i < 8; i++)
      vt32[(dg * 8 + i) * 32 + (((kp >> 2) ^ i) << 2) + (kp & 3)] =
          (unsigned int)a0.s[i] | ((unsigned int)a1.s[i] << 16);
  }
  __syncthreads();

  int buf = 0;
  for (int k0 = 0; k0 <= q0; k0 += 64) {
    const bool has_next = (k0 + 64 <= q0);
    union { uint4 u; unsigned short s[8]; } n0, n1;
    if (has_next) {
#pragma unroll
      for (int i = 0; i < 2; i++) {
        int c = i * 256 + t;
        int kr = c >> 3, cc = c & 7;
        gl_lds16(qkv + (size_t)(b * SEQ + k0 + 64 + kr) * 3072 + 1024 + h * 64 + (cc ^ (kr & 7)) * 8,
                 (char*)&Klds[buf ^ 1][0] + c * 16);
      }
      const unsigned short* vp =
          qkv + (size_t)(b * SEQ + k0 + 64 + 2 * kp) * 3072 + 2048 + h * 64 + dg * 8;
      n0.u = *(const uint4*)vp;
      n1.u = *(const uint4*)(vp + 3072);
    }

    f32x4 s[4] = {};
#pragma unroll
    for (int kk = 0; kk < 2; kk++) {
#pragma unroll
      for (int nf = 0; nf < 4; nf++) {
        int key = nf * 16 + ll;
        int cc = (kk * 4 + lg) ^ (key & 7);
        bf16x8 kf = *(const bf16x8*)((const char*)&Klds[buf][0] + key * 128 + cc * 16);
        s[nf] = __builtin_amdgcn_mfma_f32_16x16x32_bf16(kf, qf[kk], s[nf], 0, 0, 0);
      }
    }
    if (k0 == q0) {
#pragma unroll
      for (int nf = 0; nf < 4; nf++) {
        int key = k0 + nf * 16 + lg * 4;
#pragma unroll
        for (int r = 0; r < 4; r++)
          if (key + r > q_lane) s[nf][r] = -1e30f;
      }
    }
    float mx = -1e30f;
#pragma unroll
    for (int nf = 0; nf < 4; nf++)
#pragma unroll
      for (int r = 0; r < 4; r++) mx = fmaxf(mx, s[nf][r]);
    mx = fmaxf(mx, __shfl_xor(mx, 16));
    mx = fmaxf(mx, __shfl_xor(mx, 32));
    float mnew = fmaxf(mrun, mx);
    float alpha = exp2fast(mrun - mnew);
    mrun = mnew;
    float ps = 0.0f;
#pragma unroll
    for (int nf = 0; nf < 4; nf++)
#pragma unroll
      for (int r = 0; r < 4; r++) {
        float p = exp2fast(s[nf][r] - mnew);
        s[nf][r] = p;
        ps += p;
      }
    ps += __shfl_xor(ps, 16);
    ps += __shfl_xor(ps, 32);
    lrun = lrun * alpha + ps;
#pragma unroll
    for (int nf = 0; nf < 4; nf++)
#pragma unroll
      for (int r = 0; r < 4; r++) oacc[nf][r] *= alpha;

#pragma unroll
    for (int nf = 0; nf < 4; nf++) {
      unsigned int lo = (unsigned int)f2bf(s[nf][0]) | ((unsigned int)f2bf(s[nf][1]) << 16);
      unsigned int hi = (unsigned int)f2bf(s[nf][2]) | ((unsigned int)f2bf(s[nf][3]) << 16);
      int chunk = (nf * 2 + (lg >> 1)) ^ (ll & 7);
      uint2 pv; pv.x = lo; pv.y = hi;
      *(uint2*)((char*)&Plds[w][0] + ll * 128 + chunk * 16 + (lg & 1) * 8) = pv;
    }
    bf16x8 pb[2];
#pragma unroll
    for (int kk = 0; kk < 2; kk++) {
      int pc = (kk * 4 + lg) ^ (ll & 7);
      pb[kk] = *(const bf16x8*)((char*)&Plds[w][0] + ll * 128 + pc * 16);
    }
#pragma unroll
    for (int nf = 0; nf < 4; nf++) {
      int d = nf * 16 + ll;
#pragma unroll
      for (int kk = 0; kk < 2; kk++) {
        int vc = (kk * 4 + lg) ^ (d & 7);
        bf16x8 vb = *(const bf16x8*)((const char*)&Vt[buf][0] + d * 128 + vc * 16);
        oacc[nf] = __builtin_amdgcn_mfma_f32_16x16x32_bf16(vb, pb[kk], oacc[nf], 0, 0, 0);
      }
    }
    if (has_next) {
      unsigned int* vt32 = (unsigned int*)&Vt[buf ^ 1][0];
#pragma unroll
      for (int i = 0; i < 8; i++)
        vt32[(dg * 8 + i) * 32 + (((kp >> 2) ^ i) << 2) + (kp & 3)] =
            (unsigned int)n0.s[i] | ((unsigned int)n1.s[i] << 16);
    }
    __syncthreads();
    buf ^= 1;
  }

  float rl = 1.0f / lrun;
#pragma unroll
  for (int nf = 0; nf < 4; nf++) {
    ushort4 ov;
    ov.x = f2bf(oacc[nf][0] * rl);
    ov.y = f2bf(oacc[nf][1] * rl);
    ov.z = f2bf(oacc[nf][2] * rl);
    ov.w = f2bf(oacc[nf][3] * rl);
    *(ushort4*)(attn_o + (size_t)(b * SEQ + q_lane) * D_MODEL + h * 64 + nf * 16 + lg * 4) = ov;
  }
}

// ------------------------------------------------------------------------------
extern "C" void kernel_launch(void* const* d_in, const int* in_sizes, int n_in,
                              void* d_out, int out_size, void* d_ws, size_t ws_size,
                              hipStream_t stream) {
  const float* hidden_states = (const float*)d_in[0];
  const float* temb     = (const float*)d_in[2];
  const float* rope_cos = (const float*)d_in[3];
  const float* rope_sin = (const float*)d_in[4];
  const float* ln1_w    = (const float*)d_in[5];
  const float* ln1_b    = (const float*)d_in[6];
  const float* ln2_w    = (const float*)d_in[7];
  const float* ln2_b    = (const float*)d_in[8];
  const float* c_attn_w = (const float*)d_in[9];
  const float* c_attn_b = (const float*)d_in[10];
  const float* c_proj_w = (const float*)d_in[11];
  const float* c_proj_b = (const float*)d_in[12];
  const float* fc_w     = (const float*)d_in[13];
  const float* fc_b     = (const float*)d_in[14];
  const float* proj_w   = (const float*)d_in[15];
  const float* proj_b   = (const float*)d_in[16];
  const float* sst      = (const float*)d_in[17];

  char* ws = (char*)d_ws;
  unsigned short* wqkv  = (unsigned short*)(ws + 0);          // 6.29MB
  unsigned short* wproj = (unsigned short*)(ws + 6291456);    // 2.10MB
  unsigned short* wfc   = (unsigned short*)(ws + 8388608);    // 8.39MB
  unsigned short* wp2   = (unsigned short*)(ws + 16777216);   // 8.39MB (live in final)
  unsigned short* hln   = (unsigned short*)(ws + 25165824);   // 8.39MB
  unsigned short* qkvb  = (unsigned short*)(ws + 33554432);   // 25.2MB
  unsigned short* attno = (unsigned short*)(ws + 58720256);   // 8.39MB
  float*          hidden = (float*)(ws + 67108864);           // 16.8MB f32
  unsigned short* rp0 = (unsigned short*)(ws + 33554432);     // alias dead qkvb
  unsigned short* rp1 = (unsigned short*)(ws + 41943040);
  unsigned short* h3  = (unsigned short*)(ws + 33554432);     // 33.5MB (live in final)
  unsigned short* fp0 = (unsigned short*)(ws + 0);            // dead wqkv/wproj
  unsigned short* fp1 = (unsigned short*)(ws + 8388608);      // dead wfc

  dim3 tb(32, 8);
  transpose_all<<<12288, tb, 0, stream>>>(c_attn_w, c_proj_w, fc_w, proj_w,
                                          wqkv, wproj, wfc, wp2);

  ln_mod_kernel<0, 1><<<ROWS, 256, 0, stream>>>(hidden_states, ln1_w, ln1_b, sst, temb, hln);

  // qkv: 2-phase, NK=16 -> 768 blocks
  gemm64<EPI_QKV, 16><<<dim3(3072 / 128, ROWS / 128, 1), 256, 0, stream>>>(
      hln, wqkv, c_attn_b, qkvb, qkvb, 3072, 1024, rope_cos, rope_sin);

  attn_kernel<<<dim3(32 * 32), 256, 0, stream>>>(qkvb, attno);

  // attn proj: 2-phase split-K=2 (NK=8) + fused reduce+LN2
  gemm64<EPI_PART, 8><<<dim3(1024 / 128, ROWS / 128, 2), 256, 0, stream>>>(
      attno, wproj, c_proj_b, rp0, rp1, 1024, 1024, nullptr, nullptr);
  reduce_ln<<<ROWS, 256, 0, stream>>>(
      rp0, rp1, c_proj_b, sst, temb, hidden_states, hidden, ln2_w, ln2_b, hln);

  // fc+gelu: 2-phase, NK=16 -> 1024 blocks
  gemm64<EPI_GELU, 16><<<dim3(4096 / 128, ROWS / 128, 1), 256, 0, stream>>>(
      hln, wfc, fc_b, h3, h3, 4096, 1024, nullptr, nullptr);

  // mlp proj: 2-phase split-K=2 (NK=32 each) + gated reduce
  gemm64<EPI_PART, 32><<<dim3(1024 / 128, ROWS / 128, 2), 256, 0, stream>>>(
      h3, wp2, proj_b, fp0, fp1, 1024, 4096, nullptr, nullptr);
  reduce_gated<<<(ROWS * D_MODEL / 4) / 256, 256, 0, stream>>>(
      fp0, fp1, proj_b, sst, temb, 5, hidden, (float*)d_out);
}

// Round 17
// 244.752 us; speedup vs baseline: 1.0206x; 1.0206x over previous
//
#include <hip/hip_runtime.h>
#include <hip/hip_bf16.h>
#include <type_traits>

#define D_MODEL 1024
#define N_HEADS 16
#define HEAD_DIM 64
#define SEQ 2048
#define BATCH 2
#define INNER_DIM 4096
#define ROWS (BATCH*SEQ)   // 4096

using f32x4  = __attribute__((ext_vector_type(4))) float;
using bf16x8 = __attribute__((ext_vector_type(8))) short;   // 8 bf16 raw bits

__device__ __forceinline__ void gl_lds16(const void* g, void* l) {
  __builtin_amdgcn_global_load_lds(
      (const __attribute__((address_space(1))) void*)g,
      (__attribute__((address_space(3))) void*)l, 16, 0, 0);
}

__device__ __forceinline__ float bf2f(unsigned short u) {
  union { unsigned int i; float f; } v; v.i = ((unsigned int)u) << 16; return v.f;
}
__device__ __forceinline__ unsigned short f2bf(float f) {
  union { float f; unsigned int i; } v; v.f = f;
  unsigned int x = v.i;
  return (unsigned short)((x + 0x7fffu + ((x >> 16) & 1u)) >> 16);  // RTNE
}

__device__ __forceinline__ float exp2fast(float x) {
  return __builtin_amdgcn_exp2f(x);
}

__device__ __forceinline__ float gelu_tanh(float x) {
  float x3 = x * x * x;
  float z = 0.7978845608028654f * (x + 0.044715f * x3);
  z = fminf(z, 15.0f);
  float e = __expf(2.0f * z);
  float th = (e - 1.0f) / (e + 1.0f);
  return 0.5f * x * (1.0f + th);
}

// ------- fused prologue: 4 weight transposes + LN1+adaLN, one launch ----------
// bids [0,12288): transpose/convert; bids [12288,16384): ln_mod rows.
// Independent work -> concurrent execution hides the LN pass entirely.
__global__ void prologue_kernel(const float* __restrict__ w0, const float* __restrict__ w1,
                                const float* __restrict__ w2, const float* __restrict__ w3,
                                unsigned short* __restrict__ o0, unsigned short* __restrict__ o1,
                                unsigned short* __restrict__ o2, unsigned short* __restrict__ o3,
                                const float* __restrict__ x,
                                const float* __restrict__ lw,
                                const float* __restrict__ lb,
                                const float* __restrict__ sst,
                                const float* __restrict__ temb,
                                unsigned short* __restrict__ lnout) {
  int bid = blockIdx.x;
  int t = threadIdx.x;   // 256
  if (bid < 12288) {
    __shared__ float tile[32][33];
    const float* in; unsigned short* out; int K, N, nx;
    if (bid < 3072)      { in = w0; out = o0; K = 1024; N = 3072; nx = 96; }
    else if (bid < 4096) { in = w1; out = o1; K = 1024; N = 1024; nx = 32; bid -= 3072; }
    else if (bid < 8192) { in = w2; out = o2; K = 1024; N = 4096; nx = 128; bid -= 4096; }
    else                 { in = w3; out = o3; K = 4096; N = 1024; nx = 32; bid -= 8192; }
    int n0 = (bid % nx) * 32, k0 = (bid / nx) * 32;
    int tx = t & 31, ty = t >> 5;   // 32 x 8
#pragma unroll
    for (int i = 0; i < 4; i++)
      tile[ty + i * 8][tx] = in[(size_t)(k0 + ty + i * 8) * N + n0 + tx];
    __syncthreads();
#pragma unroll
    for (int i = 0; i < 4; i++)
      out[(size_t)(n0 + ty + i * 8) * K + k0 + tx] = f2bf(tile[tx][ty + i * 8]);
  } else {
    int row = bid - 12288;         // 0..4095
    int b = row >> 11;
    const float* xr = x + (size_t)row * D_MODEL;
    float4 v = ((const float4*)xr)[t];
    float s = v.x + v.y + v.z + v.w;
    float s2 = v.x * v.x + v.y * v.y + v.z * v.z + v.w * v.w;
#pragma unroll
    for (int o = 1; o < 64; o <<= 1) { s += __shfl_xor(s, o); s2 += __shfl_xor(s2, o); }
    __shared__ float red[8];
    int wid = t >> 6, lane = t & 63;
    if (lane == 0) { red[wid] = s; red[4 + wid] = s2; }
    __syncthreads();
    s = red[0] + red[1] + red[2] + red[3];
    s2 = red[4] + red[5] + red[6] + red[7];
    float mu = s * (1.0f / D_MODEL);
    float var = s2 * (1.0f / D_MODEL) - mu * mu;
    float rs = rsqrtf(var + 1e-5f);
    int d0 = t * 4;
    float xv[4] = { v.x, v.y, v.z, v.w };
    ushort4 ov;
    unsigned short* po = (unsigned short*)&ov;
#pragma unroll
    for (int j = 0; j < 4; j++) {
      int d = d0 + j;
      float ln = (xv[j] - mu) * rs * lw[d] + lb[d];
      float sc = sst[1 * D_MODEL + d] + temb[b * 6 * D_MODEL + 1 * D_MODEL + d];
      float sh = sst[0 * D_MODEL + d] + temb[b * 6 * D_MODEL + 0 * D_MODEL + d];
      po[j] = f2bf(ln * (1.0f + sc) + sh);
    }
    *((ushort4*)(lnout + (size_t)row * D_MODEL + d0)) = ov;
  }
}

// ---------------- GEMM (2-phase counted-vmcnt, R11 structure) -----------------
enum { EPI_QKV = 0, EPI_GELU = 2, EPI_PART = 3 };

template<int EPI, int NK>
__global__ __launch_bounds__(256, 2)
void gemm64(const unsigned short* __restrict__ A,
            const unsigned short* __restrict__ Bt,
            const float* __restrict__ bias,
            void* C0, void* C1,
            int N, int Kstride,
            const float* __restrict__ cosb,
            const float* __restrict__ sinb) {
  __shared__ unsigned short Alds[2][128 * 64];
  __shared__ unsigned short Blds[2][128 * 64];
  const int t = threadIdx.x;
  const int w = t >> 6, l = t & 63;
  const int lg = l >> 4, ll = l & 15;
  const int wm = w >> 1, wn = w & 1;
  const int kbase = blockIdx.z * (NK * 64);

  const int nx = gridDim.x;
  const int nwg = nx * gridDim.y;
  const int lid = blockIdx.y * nx + blockIdx.x;
  const int nid = (lid & 7) * (nwg >> 3) + (lid >> 3);
  const int m0 = (nid / nx) * 128, n0 = (nid % nx) * 128;

  void* Cout = blockIdx.z ? C1 : C0;

  f32x4 acc[4][4] = {};

  const unsigned short* ga[4];
  const unsigned short* gb[4];
#pragma unroll
  for (int i = 0; i < 4; i++) {
    int c = i * 256 + t, row = c >> 3, q = c & 7;
    ga[i] = A + (size_t)(m0 + row) * Kstride + kbase + ((q ^ (row & 7)) << 3);
    gb[i] = Bt + (size_t)(n0 + row) * Kstride + kbase + ((q ^ (row & 7)) << 3);
  }
  const unsigned short* ra[4][2];
  const unsigned short* rb[4][2];
#pragma unroll
  for (int f = 0; f < 4; f++) {
    int rowA = wm * 64 + f * 16 + ll;
    int rowB = wn * 64 + f * 16 + ll;
#pragma unroll
    for (int kk = 0; kk < 2; kk++) {
      ra[f][kk] = &Alds[0][rowA * 64 + ((((kk * 4 + lg) ^ (rowA & 7))) << 3)];
      rb[f][kk] = &Blds[0][rowB * 64 + ((((kk * 4 + lg) ^ (rowB & 7))) << 3)];
    }
  }

#pragma unroll
  for (int i = 0; i < 4; i++) {
    gl_lds16(ga[i], (char*)&Alds[0][0] + (i * 256 + t) * 16); ga[i] += 64;
  }
#pragma unroll
  for (int i = 0; i < 4; i++) {
    gl_lds16(gb[i], (char*)&Blds[0][0] + (i * 256 + t) * 16); gb[i] += 64;
  }

  auto giter = [&](auto BUFC, bool last) {
    constexpr int BUF = decltype(BUFC)::value;
    constexpr int NBUF = BUF ^ 1;
    if (!last) {
#pragma unroll
      for (int i = 0; i < 4; i++) {
        gl_lds16(ga[i], (char*)&Alds[NBUF][0] + (i * 256 + t) * 16); ga[i] += 64;
      }
#pragma unroll
      for (int i = 0; i < 4; i++) {
        gl_lds16(gb[i], (char*)&Blds[NBUF][0] + (i * 256 + t) * 16); gb[i] += 64;
      }
      asm volatile("s_waitcnt vmcnt(8)" ::: "memory");
    } else {
      asm volatile("s_waitcnt vmcnt(0)" ::: "memory");
    }
    __builtin_amdgcn_s_barrier();
    asm volatile("" ::: "memory");
#pragma unroll
    for (int kk = 0; kk < 2; kk++) {
      bf16x8 af[4], bfr[4];
#pragma unroll
      for (int mf = 0; mf < 4; mf++)
        af[mf] = *(const bf16x8*)(ra[mf][kk] + BUF * 8192);
#pragma unroll
      for (int nf = 0; nf < 4; nf++)
        bfr[nf] = *(const bf16x8*)(rb[nf][kk] + BUF * 8192);
#pragma unroll
      for (int mf = 0; mf < 4; mf++)
#pragma unroll
        for (int nf = 0; nf < 4; nf++)
          acc[mf][nf] = __builtin_amdgcn_mfma_f32_16x16x32_bf16(af[mf], bfr[nf], acc[mf][nf], 0, 0, 0);
    }
    asm volatile("" ::: "memory");
    __builtin_amdgcn_s_barrier();
  };

#pragma unroll 1
  for (int u = 0; u < NK - 2; u += 2) {
    giter(std::integral_constant<int, 0>{}, false);
    giter(std::integral_constant<int, 1>{}, false);
  }
  giter(std::integral_constant<int, 0>{}, false);
  giter(std::integral_constant<int, 1>{}, true);

#pragma unroll
  for (int mf = 0; mf < 4; mf++) {
#pragma unroll
    for (int nf = 0; nf < 4; nf++) {
      int col = n0 + wn * 64 + nf * 16 + ll;
      float bv = (EPI == EPI_PART) ? 0.0f : bias[col];
#pragma unroll
      for (int r = 0; r < 4; r++) {
        int row = m0 + wm * 64 + mf * 16 + lg * 4 + r;
        float v = acc[mf][nf][r] + bv;
        if constexpr (EPI == EPI_QKV) {
          if (col < 2048) {          // rope on q,k; pair = adjacent lane
            float vp = __shfl_xor(v, 1);
            int sp = row & (SEQ - 1);
            int ip = (col & 63) >> 1;
            float cz = cosb[sp * 32 + ip], sz = sinb[sp * 32 + ip];
            float ov = (col & 1) ? (vp * sz + v * cz) : (v * cz - vp * sz);
            if (col < 1024) ov *= 0.18033688011112042f;   // 0.125*log2e on Q
            v = ov;
          }
          ((unsigned short*)Cout)[(size_t)row * N + col] = f2bf(v);
        } else if constexpr (EPI == EPI_GELU) {
          ((unsigned short*)Cout)[(size_t)row * N + col] = f2bf(gelu_tanh(v));
        } else {   // EPI_PART: raw bf16 partial
          ((unsigned short*)Cout)[(size_t)row * N + col] = f2bf(v);
        }
      }
    }
  }
}

// ---------------- fused: hidden = (p0+p1+b)*g2 + resid; hln = LN2(hidden) -----
__global__ void reduce_ln(const unsigned short* __restrict__ p0,
                          const unsigned short* __restrict__ p1,
                          const float* __restrict__ bias,
                          const float* __restrict__ sst,
                          const float* __restrict__ temb,
                          const float* __restrict__ resid,
                          float* __restrict__ hidden,
                          const float* __restrict__ lw,
                          const float* __restrict__ lb,
                          unsigned short* __restrict__ hln) {
  int row = blockIdx.x, b = row >> 11, t = threadIdx.x;
  size_t base = (size_t)row * D_MODEL + t * 4;
  int col = t * 4;
  ushort4 a0 = *(const ushort4*)(p0 + base);
  ushort4 a1 = *(const ushort4*)(p1 + base);
  float4 rv = *(const float4*)(resid + base);
  const unsigned short* s0 = (const unsigned short*)&a0;
  const unsigned short* s1 = (const unsigned short*)&a1;
  const float* pr = (const float*)&rv;
  float h[4];
  float s = 0.0f, s2 = 0.0f;
#pragma unroll
  for (int j = 0; j < 4; j++) {
    int d = col + j;
    float g = sst[2 * D_MODEL + d] + temb[b * 6 * D_MODEL + 2 * D_MODEL + d];
    float v = (bf2f(s0[j]) + bf2f(s1[j]) + bias[d]) * g + pr[j];
    h[j] = v; s += v; s2 += v * v;
  }
  float4 hv; hv.x = h[0]; hv.y = h[1]; hv.z = h[2]; hv.w = h[3];
  *(float4*)(hidden + base) = hv;
#pragma unroll
  for (int o = 1; o < 64; o <<= 1) { s += __shfl_xor(s, o); s2 += __shfl_xor(s2, o); }
  __shared__ float red[8];
  int wid = t >> 6, lane = t & 63;
  if (lane == 0) { red[wid] = s; red[4 + wid] = s2; }
  __syncthreads();
  s = red[0] + red[1] + red[2] + red[3];
  s2 = red[4] + red[5] + red[6] + red[7];
  float mu = s * (1.0f / D_MODEL);
  float var = s2 * (1.0f / D_MODEL) - mu * mu;
  float rs = rsqrtf(var + 1e-5f);
  ushort4 ov;
  unsigned short* po = (unsigned short*)&ov;
#pragma unroll
  for (int j = 0; j < 4; j++) {
    int d = col + j;
    float ln = (h[j] - mu) * rs * lw[d] + lb[d];
    float sc = sst[4 * D_MODEL + d] + temb[b * 6 * D_MODEL + 4 * D_MODEL + d];
    float sh = sst[3 * D_MODEL + d] + temb[b * 6 * D_MODEL + 3 * D_MODEL + d];
    po[j] = f2bf(ln * (1.0f + sc) + sh);
  }
  *(ushort4*)(hln + base) = ov;
}

// ---------------- reduce: out_f32 = (p0+p1+bias)*g + resid --------------------
__global__ void reduce_gated(const unsigned short* __restrict__ p0,
                             const unsigned short* __restrict__ p1,
                             const float* __restrict__ bias,
                             const float* __restrict__ sst,
                             const float* __restrict__ temb,
                             int g_idx,
                             const float* __restrict__ resid,
                             float* __restrict__ out) {
  int i = blockIdx.x * 256 + threadIdx.x;
  int idx = i * 4;
  int col = idx & 1023;
  int b = idx >> 21;
  ushort4 a0 = *(const ushort4*)(p0 + idx);
  ushort4 a1 = *(const ushort4*)(p1 + idx);
  float4 rv = *(const float4*)(resid + idx);
  float4 o;
  const unsigned short* s0 = (const unsigned short*)&a0;
  const unsigned short* s1 = (const unsigned short*)&a1;
  float* po = (float*)&o;
  const float* pr = (const float*)&rv;
#pragma unroll
  for (int j = 0; j < 4; j++) {
    float s = bf2f(s0[j]) + bf2f(s1[j]) + bias[col + j];
    float g = sst[g_idx * D_MODEL + col + j] + temb[b * 6 * D_MODEL + g_idx * D_MODEL + col + j];
    po[j] = s * g + pr[j];
  }
  *(float4*)(out + idx) = o;
}

// ---------------- Flash attention (causal), swapped-operand softmax -----------
__global__ __launch_bounds__(256, 4)
void attn_kernel(const unsigned short* __restrict__ qkv,
                 unsigned short* __restrict__ attn_o) {
  __shared__ unsigned short Klds[2][64 * 64];
  __shared__ unsigned short Vt[2][64 * 64];
  __shared__ unsigned short Plds[4][16 * 64];

  const int id = blockIdx.x;
  const int bh = id & 31;
  const int b = bh >> 4, h = bh & 15;
  const int q0 = (31 - (id >> 5)) * 64;   // longest blocks first
  const int t = threadIdx.x;
  const int w = t >> 6, l = t & 63;
  const int lg = l >> 4, ll = l & 15;
  const int qw0 = q0 + w * 16;
  const int q_lane = qw0 + ll;

  bf16x8 qf[2];
  {
    const unsigned short* qb = qkv + (size_t)(b * SEQ + q_lane) * 3072 + h * 64;
    qf[0] = *(const bf16x8*)(qb + lg * 8);
    qf[1] = *(const bf16x8*)(qb + 32 + lg * 8);
  }

  const int kp = t & 31, dg = t >> 5;

  f32x4 oacc[4] = {};
  float mrun = -1e30f, lrun = 0.0f;

  {
#pragma unroll
    for (int i = 0; i < 2; i++) {
      int c = i * 256 + t;
      int kr = c >> 3, cc = c & 7;
      gl_lds16(qkv + (size_t)(b * SEQ + kr) * 3072 + 1024 + h * 64 + (cc ^ (kr & 7)) * 8,
               (char*)&Klds[0][0] + c * 16);
    }
    const unsigned short* vp = qkv + (size_t)(b * SEQ + 2 * kp) * 3072 + 2048 + h * 64 + dg * 8;
    union { uint4 u; unsigned short s[8]; } a0, a1;
    a0.u = *(const uint4*)vp;
    a1.u = *(const uint4*)(vp + 3072);
    unsigned int* vt32 = (unsigned int*)&Vt[0][0];
#pragma unroll
    for (int i = 0; i < 8; i++)
      vt32[(dg * 8 + i) * 32 + (((kp >> 2) ^ i) << 2) + (kp & 3)] =
          (unsigned int)a0.s[i] | ((unsigned int)a1.s[i] << 16);
  }
  __syncthreads();

  int buf = 0;
  for (int k0 = 0; k0 <= q0; k0 += 64) {
    const bool has_next = (k0 + 64 <= q0);
    union { uint4 u; unsigned short s[8]; } n0, n1;
    if (has_next) {
#pragma unroll
      for (int i = 0; i < 2; i++) {
        int c = i * 256 + t;
        int kr = c >> 3, cc = c & 7;
        gl_lds16(qkv + (size_t)(b * SEQ + k0 + 64 + kr) * 3072 + 1024 + h * 64 + (cc ^ (kr & 7)) * 8,
                 (char*)&Klds[buf ^ 1][0] + c * 16);
      }
      const unsigned short* vp =
          qkv + (size_t)(b * SEQ + k0 + 64 + 2 * kp) * 3072 + 2048 + h * 64 + dg * 8;
      n0.u = *(const uint4*)vp;
      n1.u = *(const uint4*)(vp + 3072);
    }

    f32x4 s[4] = {};
#pragma unroll
    for (int kk = 0; kk < 2; kk++) {
#pragma unroll
      for (int nf = 0; nf < 4; nf++) {
        int key = nf * 16 + ll;
        int cc = (kk * 4 + lg) ^ (key & 7);
        bf16x8 kf = *(const bf16x8*)((const char*)&Klds[buf][0] + key * 128 + cc * 16);
        s[nf] = __builtin_amdgcn_mfma_f32_16x16x32_bf16(kf, qf[kk], s[nf], 0, 0, 0);
      }
    }
    if (k0 == q0) {
#pragma unroll
      for (int nf = 0; nf < 4; nf++) {
        int key = k0 + nf * 16 + lg * 4;
#pragma unroll
        for (int r = 0; r < 4; r++)
          if (key + r > q_lane) s[nf][r] = -1e30f;
      }
    }
    float mx = -1e30f;
#pragma unroll
    for (int nf = 0; nf < 4; nf++)
#pragma unroll
      for (int r = 0; r < 4; r++) mx = fmaxf(mx, s[nf][r]);
    mx = fmaxf(mx, __shfl_xor(mx, 16));
    mx = fmaxf(mx, __shfl_xor(mx, 32));
    float mnew = fmaxf(mrun, mx);
    float alpha = exp2fast(mrun - mnew);
    mrun = mnew;
    float ps = 0.0f;
#pragma unroll
    for (int nf = 0; nf < 4; nf++)
#pragma unroll
      for (int r = 0; r < 4; r++) {
        float p = exp2fast(s[nf][r] - mnew);
        s[nf][r] = p;
        ps += p;
      }
    ps += __shfl_xor(ps, 16);
    ps += __shfl_xor(ps, 32);
    lrun = lrun * alpha + ps;
#pragma unroll
    for (int nf = 0; nf < 4; nf++)
#pragma unroll
      for (int r = 0; r < 4; r++) oacc[nf][r] *= alpha;

#pragma unroll
    for (int nf = 0; nf < 4; nf++) {
      unsigned int lo = (unsigned int)f2bf(s[nf][0]) | ((unsigned int)f2bf(s[nf][1]) << 16);
      unsigned int hi = (unsigned int)f2bf(s[nf][2]) | ((unsigned int)f2bf(s[nf][3]) << 16);
      int chunk = (nf * 2 + (lg >> 1)) ^ (ll & 7);
      uint2 pv; pv.x = lo; pv.y = hi;
      *(uint2*)((char*)&Plds[w][0] + ll * 128 + chunk * 16 + (lg & 1) * 8) = pv;
    }
    bf16x8 pb[2];
#pragma unroll
    for (int kk = 0; kk < 2; kk++) {
      int pc = (kk * 4 + lg) ^ (ll & 7);
      pb[kk] = *(const bf16x8*)((char*)&Plds[w][0] + ll * 128 + pc * 16);
    }
#pragma unroll
    for (int nf = 0; nf < 4; nf++) {
      int d = nf * 16 + ll;
#pragma unroll
      for (int kk = 0; kk < 2; kk++) {
        int vc = (kk * 4 + lg) ^ (d & 7);
        bf16x8 vb = *(const bf16x8*)((const char*)&Vt[buf][0] + d * 128 + vc * 16);
        oacc[nf] = __builtin_amdgcn_mfma_f32_16x16x32_bf16(vb, pb[kk], oacc[nf], 0, 0, 0);
      }
    }
    if (has_next) {
      unsigned int* vt32 = (unsigned int*)&Vt[buf ^ 1][0];
#pragma unroll
      for (int i = 0; i < 8; i++)
        vt32[(dg * 8 + i) * 32 + (((kp >> 2) ^ i) << 2) + (kp & 3)] =
            (unsigned int)n0.s[i] | ((unsigned int)n1.s[i] << 16);
    }
    __syncthreads();
    buf ^= 1;
  }

  float rl = 1.0f / lrun;
#pragma unroll
  for (int nf = 0; nf < 4; nf++) {
    ushort4 ov;
    ov.x = f2bf(oacc[nf][0] * rl);
    ov.y = f2bf(oacc[nf][1] * rl);
    ov.z = f2bf(oacc[nf][2] * rl);
    ov.w = f2bf(oacc[nf][3] * rl);
    *(ushort4*)(attn_o + (size_t)(b * SEQ + q_lane) * D_MODEL + h * 64 + nf * 16 + lg * 4) = ov;
  }
}

// ------------------------------------------------------------------------------
extern "C" void kernel_launch(void* const* d_in, const int* in_sizes, int n_in,
                              void* d_out, int out_size, void* d_ws, size_t ws_size,
                              hipStream_t stream) {
  const float* hidden_states = (const float*)d_in[0];
  const float* temb     = (const float*)d_in[2];
  const float* rope_cos = (const float*)d_in[3];
  const float* rope_sin = (const float*)d_in[4];
  const float* ln1_w    = (const float*)d_in[5];
  const float* ln1_b    = (const float*)d_in[6];
  const float* ln2_w    = (const float*)d_in[7];
  const float* ln2_b    = (const float*)d_in[8];
  const float* c_attn_w = (const float*)d_in[9];
  const float* c_attn_b = (const float*)d_in[10];
  const float* c_proj_w = (const float*)d_in[11];
  const float* c_proj_b = (const float*)d_in[12];
  const float* fc_w     = (const float*)d_in[13];
  const float* fc_b     = (const float*)d_in[14];
  const float* proj_w   = (const float*)d_in[15];
  const float* proj_b   = (const float*)d_in[16];
  const float* sst      = (const float*)d_in[17];

  char* ws = (char*)d_ws;
  unsigned short* wqkv  = (unsigned short*)(ws + 0);          // 6.29MB
  unsigned short* wproj = (unsigned short*)(ws + 6291456);    // 2.10MB
  unsigned short* wfc   = (unsigned short*)(ws + 8388608);    // 8.39MB
  unsigned short* wp2   = (unsigned short*)(ws + 16777216);   // 8.39MB (live in final)
  unsigned short* hln   = (unsigned short*)(ws + 25165824);   // 8.39MB
  unsigned short* qkvb  = (unsigned short*)(ws + 33554432);   // 25.2MB
  unsigned short* attno = (unsigned short*)(ws + 58720256);   // 8.39MB
  float*          hidden = (float*)(ws + 67108864);           // 16.8MB f32
  unsigned short* rp0 = (unsigned short*)(ws + 33554432);     // alias dead qkvb
  unsigned short* rp1 = (unsigned short*)(ws + 41943040);
  unsigned short* h3  = (unsigned short*)(ws + 33554432);     // 33.5MB (live in final)
  unsigned short* fp0 = (unsigned short*)(ws + 0);            // dead wqkv/wproj
  unsigned short* fp1 = (unsigned short*)(ws + 8388608);      // dead wfc

  // prologue: weight transposes + LN1 modulation (independent, one launch)
  prologue_kernel<<<16384, 256, 0, stream>>>(
      c_attn_w, c_proj_w, fc_w, proj_w, wqkv, wproj, wfc, wp2,
      hidden_states, ln1_w, ln1_b, sst, temb, hln);

  // qkv: 2-phase, NK=16 -> 768 blocks
  gemm64<EPI_QKV, 16><<<dim3(3072 / 128, ROWS / 128, 1), 256, 0, stream>>>(
      hln, wqkv, c_attn_b, qkvb, qkvb, 3072, 1024, rope_cos, rope_sin);

  attn_kernel<<<dim3(32 * 32), 256, 0, stream>>>(qkvb, attno);

  // attn proj: 2-phase split-K=2 (NK=8) + fused reduce+LN2
  gemm64<EPI_PART, 8><<<dim3(1024 / 128, ROWS / 128, 2), 256, 0, stream>>>(
      attno, wproj, c_proj_b, rp0, rp1, 1024, 1024, nullptr, nullptr);
  reduce_ln<<<ROWS, 256, 0, stream>>>(
      rp0, rp1, c_proj_b, sst, temb, hidden_states, hidden, ln2_w, ln2_b, hln);

  // fc+gelu: 2-phase, NK=16 -> 1024 blocks
  gemm64<EPI_GELU, 16><<<dim3(4096 / 128, ROWS / 128, 1), 256, 0, stream>>>(
      hln, wfc, fc_b, h3, h3, 4096, 1024, nullptr, nullptr);

  // mlp proj: 2-phase split-K=2 (NK=32 each) + gated reduce
  gemm64<EPI_PART, 32><<<dim3(1024 / 128, ROWS / 128, 2), 256, 0, stream>>>(
      h3, wp2, proj_b, fp0, fp1, 1024, 4096, nullptr, nullptr);
  reduce_gated<<<(ROWS * D_MODEL / 4) / 256, 256, 0, stream>>>(
      fp0, fp1, proj_b, sst, temb, 5, hidden, (float*)d_out);
}

// Round 18
// 243.310 us; speedup vs baseline: 1.0266x; 1.0059x over previous
//
#include <hip/hip_runtime.h>
#include <hip/hip_bf16.h>
#include <type_traits>

#define D_MODEL 1024
#define N_HEADS 16
#define HEAD_DIM 64
#define SEQ 2048
#define BATCH 2
#define INNER_DIM 4096
#define ROWS (BATCH*SEQ)   // 4096

using f32x4  = __attribute__((ext_vector_type(4))) float;
using bf16x8 = __attribute__((ext_vector_type(8))) short;   // 8 bf16 raw bits

__device__ __forceinline__ void gl_lds16(const void* g, void* l) {
  __builtin_amdgcn_global_load_lds(
      (const __attribute__((address_space(1))) void*)g,
      (__attribute__((address_space(3))) void*)l, 16, 0, 0);
}

__device__ __forceinline__ float bf2f(unsigned short u) {
  union { unsigned int i; float f; } v; v.i = ((unsigned int)u) << 16; return v.f;
}
__device__ __forceinline__ unsigned short f2bf(float f) {
  union { float f; unsigned int i; } v; v.f = f;
  unsigned int x = v.i;
  return (unsigned short)((x + 0x7fffu + ((x >> 16) & 1u)) >> 16);  // RTNE
}

__device__ __forceinline__ float exp2fast(float x) {
  return __builtin_amdgcn_exp2f(x);
}

__device__ __forceinline__ float gelu_tanh(float x) {
  float x3 = x * x * x;
  float z = 0.7978845608028654f * (x + 0.044715f * x3);
  z = fminf(z, 15.0f);
  float e = __expf(2.0f * z);
  float th = (e - 1.0f) / (e + 1.0f);
  return 0.5f * x * (1.0f + th);
}

// ------- fused prologue: 4 weight transposes + LN1+adaLN, one launch ----------
__global__ void prologue_kernel(const float* __restrict__ w0, const float* __restrict__ w1,
                                const float* __restrict__ w2, const float* __restrict__ w3,
                                unsigned short* __restrict__ o0, unsigned short* __restrict__ o1,
                                unsigned short* __restrict__ o2, unsigned short* __restrict__ o3,
                                const float* __restrict__ x,
                                const float* __restrict__ lw,
                                const float* __restrict__ lb,
                                const float* __restrict__ sst,
                                const float* __restrict__ temb,
                                unsigned short* __restrict__ lnout) {
  int bid = blockIdx.x;
  int t = threadIdx.x;   // 256
  if (bid < 12288) {
    __shared__ float tile[32][33];
    const float* in; unsigned short* out; int K, N, nx;
    if (bid < 3072)      { in = w0; out = o0; K = 1024; N = 3072; nx = 96; }
    else if (bid < 4096) { in = w1; out = o1; K = 1024; N = 1024; nx = 32; bid -= 3072; }
    else if (bid < 8192) { in = w2; out = o2; K = 1024; N = 4096; nx = 128; bid -= 4096; }
    else                 { in = w3; out = o3; K = 4096; N = 1024; nx = 32; bid -= 8192; }
    int n0 = (bid % nx) * 32, k0 = (bid / nx) * 32;
    int tx = t & 31, ty = t >> 5;   // 32 x 8
#pragma unroll
    for (int i = 0; i < 4; i++)
      tile[ty + i * 8][tx] = in[(size_t)(k0 + ty + i * 8) * N + n0 + tx];
    __syncthreads();
#pragma unroll
    for (int i = 0; i < 4; i++)
      out[(size_t)(n0 + ty + i * 8) * K + k0 + tx] = f2bf(tile[tx][ty + i * 8]);
  } else {
    int row = bid - 12288;         // 0..4095
    int b = row >> 11;
    const float* xr = x + (size_t)row * D_MODEL;
    float4 v = ((const float4*)xr)[t];
    float s = v.x + v.y + v.z + v.w;
    float s2 = v.x * v.x + v.y * v.y + v.z * v.z + v.w * v.w;
#pragma unroll
    for (int o = 1; o < 64; o <<= 1) { s += __shfl_xor(s, o); s2 += __shfl_xor(s2, o); }
    __shared__ float red[8];
    int wid = t >> 6, lane = t & 63;
    if (lane == 0) { red[wid] = s; red[4 + wid] = s2; }
    __syncthreads();
    s = red[0] + red[1] + red[2] + red[3];
    s2 = red[4] + red[5] + red[6] + red[7];
    float mu = s * (1.0f / D_MODEL);
    float var = s2 * (1.0f / D_MODEL) - mu * mu;
    float rs = rsqrtf(var + 1e-5f);
    int d0 = t * 4;
    float xv[4] = { v.x, v.y, v.z, v.w };
    ushort4 ov;
    unsigned short* po = (unsigned short*)&ov;
#pragma unroll
    for (int j = 0; j < 4; j++) {
      int d = d0 + j;
      float ln = (xv[j] - mu) * rs * lw[d] + lb[d];
      float sc = sst[1 * D_MODEL + d] + temb[b * 6 * D_MODEL + 1 * D_MODEL + d];
      float sh = sst[0 * D_MODEL + d] + temb[b * 6 * D_MODEL + 0 * D_MODEL + d];
      po[j] = f2bf(ln * (1.0f + sc) + sh);
    }
    *((ushort4*)(lnout + (size_t)row * D_MODEL + d0)) = ov;
  }
}

// ---------------- GEMM (2-phase counted-vmcnt, R11 structure) -----------------
enum { EPI_QKV = 0, EPI_GELU = 2, EPI_PART = 3 };

template<int EPI, int NK>
__global__ __launch_bounds__(256, 2)
void gemm64(const unsigned short* __restrict__ A,
            const unsigned short* __restrict__ Bt,
            const float* __restrict__ bias,
            void* C0, void* C1,
            int N, int Kstride,
            const float* __restrict__ cosb,
            const float* __restrict__ sinb) {
  __shared__ unsigned short Alds[2][128 * 64];
  __shared__ unsigned short Blds[2][128 * 64];
  const int t = threadIdx.x;
  const int w = t >> 6, l = t & 63;
  const int lg = l >> 4, ll = l & 15;
  const int wm = w >> 1, wn = w & 1;
  const int kbase = blockIdx.z * (NK * 64);

  const int nx = gridDim.x;
  const int nwg = nx * gridDim.y;
  const int lid = blockIdx.y * nx + blockIdx.x;
  const int nid = (lid & 7) * (nwg >> 3) + (lid >> 3);
  const int m0 = (nid / nx) * 128, n0 = (nid % nx) * 128;

  void* Cout = blockIdx.z ? C1 : C0;

  f32x4 acc[4][4] = {};

  const unsigned short* ga[4];
  const unsigned short* gb[4];
#pragma unroll
  for (int i = 0; i < 4; i++) {
    int c = i * 256 + t, row = c >> 3, q = c & 7;
    ga[i] = A + (size_t)(m0 + row) * Kstride + kbase + ((q ^ (row & 7)) << 3);
    gb[i] = Bt + (size_t)(n0 + row) * Kstride + kbase + ((q ^ (row & 7)) << 3);
  }
  const unsigned short* ra[4][2];
  const unsigned short* rb[4][2];
#pragma unroll
  for (int f = 0; f < 4; f++) {
    int rowA = wm * 64 + f * 16 + ll;
    int rowB = wn * 64 + f * 16 + ll;
#pragma unroll
    for (int kk = 0; kk < 2; kk++) {
      ra[f][kk] = &Alds[0][rowA * 64 + ((((kk * 4 + lg) ^ (rowA & 7))) << 3)];
      rb[f][kk] = &Blds[0][rowB * 64 + ((((kk * 4 + lg) ^ (rowB & 7))) << 3)];
    }
  }

#pragma unroll
  for (int i = 0; i < 4; i++) {
    gl_lds16(ga[i], (char*)&Alds[0][0] + (i * 256 + t) * 16); ga[i] += 64;
  }
#pragma unroll
  for (int i = 0; i < 4; i++) {
    gl_lds16(gb[i], (char*)&Blds[0][0] + (i * 256 + t) * 16); gb[i] += 64;
  }

  auto giter = [&](auto BUFC, bool last) {
    constexpr int BUF = decltype(BUFC)::value;
    constexpr int NBUF = BUF ^ 1;
    if (!last) {
#pragma unroll
      for (int i = 0; i < 4; i++) {
        gl_lds16(ga[i], (char*)&Alds[NBUF][0] + (i * 256 + t) * 16); ga[i] += 64;
      }
#pragma unroll
      for (int i = 0; i < 4; i++) {
        gl_lds16(gb[i], (char*)&Blds[NBUF][0] + (i * 256 + t) * 16); gb[i] += 64;
      }
      asm volatile("s_waitcnt vmcnt(8)" ::: "memory");
    } else {
      asm volatile("s_waitcnt vmcnt(0)" ::: "memory");
    }
    __builtin_amdgcn_s_barrier();
    asm volatile("" ::: "memory");
#pragma unroll
    for (int kk = 0; kk < 2; kk++) {
      bf16x8 af[4], bfr[4];
#pragma unroll
      for (int mf = 0; mf < 4; mf++)
        af[mf] = *(const bf16x8*)(ra[mf][kk] + BUF * 8192);
#pragma unroll
      for (int nf = 0; nf < 4; nf++)
        bfr[nf] = *(const bf16x8*)(rb[nf][kk] + BUF * 8192);
#pragma unroll
      for (int mf = 0; mf < 4; mf++)
#pragma unroll
        for (int nf = 0; nf < 4; nf++)
          acc[mf][nf] = __builtin_amdgcn_mfma_f32_16x16x32_bf16(af[mf], bfr[nf], acc[mf][nf], 0, 0, 0);
    }
    asm volatile("" ::: "memory");
    __builtin_amdgcn_s_barrier();
  };

#pragma unroll 1
  for (int u = 0; u < NK - 2; u += 2) {
    giter(std::integral_constant<int, 0>{}, false);
    giter(std::integral_constant<int, 1>{}, false);
  }
  giter(std::integral_constant<int, 0>{}, false);
  giter(std::integral_constant<int, 1>{}, true);

#pragma unroll
  for (int mf = 0; mf < 4; mf++) {
#pragma unroll
    for (int nf = 0; nf < 4; nf++) {
      int col = n0 + wn * 64 + nf * 16 + ll;
      float bv = (EPI == EPI_PART) ? 0.0f : bias[col];
#pragma unroll
      for (int r = 0; r < 4; r++) {
        int row = m0 + wm * 64 + mf * 16 + lg * 4 + r;
        float v = acc[mf][nf][r] + bv;
        if constexpr (EPI == EPI_QKV) {
          if (col < 2048) {          // rope on q,k; pair = adjacent lane
            float vp = __shfl_xor(v, 1);
            int sp = row & (SEQ - 1);
            int ip = (col & 63) >> 1;
            float cz = cosb[sp * 32 + ip], sz = sinb[sp * 32 + ip];
            float ov = (col & 1) ? (vp * sz + v * cz) : (v * cz - vp * sz);
            if (col < 1024) ov *= 0.18033688011112042f;   // 0.125*log2e on Q
            v = ov;
          }
          ((unsigned short*)Cout)[(size_t)row * N + col] = f2bf(v);
        } else if constexpr (EPI == EPI_GELU) {
          ((unsigned short*)Cout)[(size_t)row * N + col] = f2bf(gelu_tanh(v));
        } else {   // EPI_PART: raw bf16 partial
          ((unsigned short*)Cout)[(size_t)row * N + col] = f2bf(v);
        }
      }
    }
  }
}

// -------- fused: hidden_bf16 = (p0+p1+b)*g2 + resid; hln = LN2(hidden) -------
// LN2 uses full-f32 h in-register; only the STORED residual copy is bf16.
__global__ void reduce_ln(const unsigned short* __restrict__ p0,
                          const unsigned short* __restrict__ p1,
                          const float* __restrict__ bias,
                          const float* __restrict__ sst,
                          const float* __restrict__ temb,
                          const float* __restrict__ resid,
                          unsigned short* __restrict__ hiddenb,
                          const float* __restrict__ lw,
                          const float* __restrict__ lb,
                          unsigned short* __restrict__ hln) {
  int row = blockIdx.x, b = row >> 11, t = threadIdx.x;
  size_t base = (size_t)row * D_MODEL + t * 4;
  int col = t * 4;
  ushort4 a0 = *(const ushort4*)(p0 + base);
  ushort4 a1 = *(const ushort4*)(p1 + base);
  float4 rv = *(const float4*)(resid + base);
  const unsigned short* s0 = (const unsigned short*)&a0;
  const unsigned short* s1 = (const unsigned short*)&a1;
  const float* pr = (const float*)&rv;
  float h[4];
  float s = 0.0f, s2 = 0.0f;
#pragma unroll
  for (int j = 0; j < 4; j++) {
    int d = col + j;
    float g = sst[2 * D_MODEL + d] + temb[b * 6 * D_MODEL + 2 * D_MODEL + d];
    float v = (bf2f(s0[j]) + bf2f(s1[j]) + bias[d]) * g + pr[j];
    h[j] = v; s += v; s2 += v * v;
  }
  ushort4 hb;
  unsigned short* ph = (unsigned short*)&hb;
#pragma unroll
  for (int j = 0; j < 4; j++) ph[j] = f2bf(h[j]);
  *(ushort4*)(hiddenb + base) = hb;
#pragma unroll
  for (int o = 1; o < 64; o <<= 1) { s += __shfl_xor(s, o); s2 += __shfl_xor(s2, o); }
  __shared__ float red[8];
  int wid = t >> 6, lane = t & 63;
  if (lane == 0) { red[wid] = s; red[4 + wid] = s2; }
  __syncthreads();
  s = red[0] + red[1] + red[2] + red[3];
  s2 = red[4] + red[5] + red[6] + red[7];
  float mu = s * (1.0f / D_MODEL);
  float var = s2 * (1.0f / D_MODEL) - mu * mu;
  float rs = rsqrtf(var + 1e-5f);
  ushort4 ov;
  unsigned short* po = (unsigned short*)&ov;
#pragma unroll
  for (int j = 0; j < 4; j++) {
    int d = col + j;
    float ln = (h[j] - mu) * rs * lw[d] + lb[d];
    float sc = sst[4 * D_MODEL + d] + temb[b * 6 * D_MODEL + 4 * D_MODEL + d];
    float sh = sst[3 * D_MODEL + d] + temb[b * 6 * D_MODEL + 3 * D_MODEL + d];
    po[j] = f2bf(ln * (1.0f + sc) + sh);
  }
  *(ushort4*)(hln + base) = ov;
}

// ---------------- reduce: out_f32 = (p0+p1+bias)*g + resid_bf16 ---------------
__global__ void reduce_gated(const unsigned short* __restrict__ p0,
                             const unsigned short* __restrict__ p1,
                             const float* __restrict__ bias,
                             const float* __restrict__ sst,
                             const float* __restrict__ temb,
                             int g_idx,
                             const unsigned short* __restrict__ residb,
                             float* __restrict__ out) {
  int i = blockIdx.x * 256 + threadIdx.x;
  int idx = i * 4;
  int col = idx & 1023;
  int b = idx >> 21;
  ushort4 a0 = *(const ushort4*)(p0 + idx);
  ushort4 a1 = *(const ushort4*)(p1 + idx);
  ushort4 rb = *(const ushort4*)(residb + idx);
  float4 o;
  const unsigned short* s0 = (const unsigned short*)&a0;
  const unsigned short* s1 = (const unsigned short*)&a1;
  const unsigned short* pr = (const unsigned short*)&rb;
  float* po = (float*)&o;
#pragma unroll
  for (int j = 0; j < 4; j++) {
    float s = bf2f(s0[j]) + bf2f(s1[j]) + bias[col + j];
    float g = sst[g_idx * D_MODEL + col + j] + temb[b * 6 * D_MODEL + g_idx * D_MODEL + col + j];
    po[j] = s * g + bf2f(pr[j]);
  }
  *(float4*)(out + idx) = o;
}

// ---------------- Flash attention (causal), swapped-operand softmax -----------
__global__ __launch_bounds__(256, 4)
void attn_kernel(const unsigned short* __restrict__ qkv,
                 unsigned short* __restrict__ attn_o) {
  __shared__ unsigned short Klds[2][64 * 64];
  __shared__ unsigned short Vt[2][64 * 64];
  __shared__ unsigned short Plds[4][16 * 64];

  const int id = blockIdx.x;
  const int bh = id & 31;
  const int b = bh >> 4, h = bh & 15;
  const int q0 = (31 - (id >> 5)) * 64;   // longest blocks first
  const int t = threadIdx.x;
  const int w = t >> 6, l = t & 63;
  const int lg = l >> 4, ll = l & 15;
  const int qw0 = q0 + w * 16;
  const int q_lane = qw0 + ll;

  bf16x8 qf[2];
  {
    const unsigned short* qb = qkv + (size_t)(b * SEQ + q_lane) * 3072 + h * 64;
    qf[0] = *(const bf16x8*)(qb + lg * 8);
    qf[1] = *(const bf16x8*)(qb + 32 + lg * 8);
  }

  const int kp = t & 31, dg = t >> 5;

  f32x4 oacc[4] = {};
  float mrun = -1e30f, lrun = 0.0f;

  {
#pragma unroll
    for (int i = 0; i < 2; i++) {
      int c = i * 256 + t;
      int kr = c >> 3, cc = c & 7;
      gl_lds16(qkv + (size_t)(b * SEQ + kr) * 3072 + 1024 + h * 64 + (cc ^ (kr & 7)) * 8,
               (char*)&Klds[0][0] + c * 16);
    }
    const unsigned short* vp = qkv + (size_t)(b * SEQ + 2 * kp) * 3072 + 2048 + h * 64 + dg * 8;
    union { uint4 u; unsigned short s[8]; } a0, a1;
    a0.u = *(const uint4*)vp;
    a1.u = *(const uint4*)(vp + 3072);
    unsigned int* vt32 = (unsigned int*)&Vt[0][0];
#pragma unroll
    for (int i = 0; i < 8; i++)
      vt32[(dg * 8 + i) * 32 + (((kp >> 2) ^ i) << 2) + (kp & 3)] =
          (unsigned int)a0.s[i] | ((unsigned int)a1.s[i] << 16);
  }
  __syncthreads();

  int buf = 0;
  for (int k0 = 0; k0 <= q0; k0 += 64) {
    const bool has_next = (k0 + 64 <= q0);
    union { uint4 u; unsigned short s[8]; } n0, n1;
    if (has_next) {
#pragma unroll
      for (int i = 0; i < 2; i++) {
        int c = i * 256 + t;
        int kr = c >> 3, cc = c & 7;
        gl_lds16(qkv + (size_t)(b * SEQ + k0 + 64 + kr) * 3072 + 1024 + h * 64 + (cc ^ (kr & 7)) * 8,
                 (char*)&Klds[buf ^ 1][0] + c * 16);
      }
      const unsigned short* vp =
          qkv + (size_t)(b * SEQ + k0 + 64 + 2 * kp) * 3072 + 2048 + h * 64 + dg * 8;
      n0.u = *(const uint4*)vp;
      n1.u = *(const uint4*)(vp + 3072);
    }

    f32x4 s[4] = {};
#pragma unroll
    for (int kk = 0; kk < 2; kk++) {
#pragma unroll
      for (int nf = 0; nf < 4; nf++) {
        int key = nf * 16 + ll;
        int cc = (kk * 4 + lg) ^ (key & 7);
        bf16x8 kf = *(const bf16x8*)((const char*)&Klds[buf][0] + key * 128 + cc * 16);
        s[nf] = __builtin_amdgcn_mfma_f32_16x16x32_bf16(kf, qf[kk], s[nf], 0, 0, 0);
      }
    }
    if (k0 == q0) {
#pragma unroll
      for (int nf = 0; nf < 4; nf++) {
        int key = k0 + nf * 16 + lg * 4;
#pragma unroll
        for (int r = 0; r < 4; r++)
          if (key + r > q_lane) s[nf][r] = -1e30f;
      }
    }
    float mx = -1e30f;
#pragma unroll
    for (int nf = 0; nf < 4; nf++)
#pragma unroll
      for (int r = 0; r < 4; r++) mx = fmaxf(mx, s[nf][r]);
    mx = fmaxf(mx, __shfl_xor(mx, 16));
    mx = fmaxf(mx, __shfl_xor(mx, 32));
    float mnew = fmaxf(mrun, mx);
    float alpha = exp2fast(mrun - mnew);
    mrun = mnew;
    float ps = 0.0f;
#pragma unroll
    for (int nf = 0; nf < 4; nf++)
#pragma unroll
      for (int r = 0; r < 4; r++) {
        float p = exp2fast(s[nf][r] - mnew);
        s[nf][r] = p;
        ps += p;
      }
    ps += __shfl_xor(ps, 16);
    ps += __shfl_xor(ps, 32);
    lrun = lrun * alpha + ps;
#pragma unroll
    for (int nf = 0; nf < 4; nf++)
#pragma unroll
      for (int r = 0; r < 4; r++) oacc[nf][r] *= alpha;

#pragma unroll
    for (int nf = 0; nf < 4; nf++) {
      unsigned int lo = (unsigned int)f2bf(s[nf][0]) | ((unsigned int)f2bf(s[nf][1]) << 16);
      unsigned int hi = (unsigned int)f2bf(s[nf][2]) | ((unsigned int)f2bf(s[nf][3]) << 16);
      int chunk = (nf * 2 + (lg >> 1)) ^ (ll & 7);
      uint2 pv; pv.x = lo; pv.y = hi;
      *(uint2*)((char*)&Plds[w][0] + ll * 128 + chunk * 16 + (lg & 1) * 8) = pv;
    }
    bf16x8 pb[2];
#pragma unroll
    for (int kk = 0; kk < 2; kk++) {
      int pc = (kk * 4 + lg) ^ (ll & 7);
      pb[kk] = *(const bf16x8*)((char*)&Plds[w][0] + ll * 128 + pc * 16);
    }
#pragma unroll
    for (int nf = 0; nf < 4; nf++) {
      int d = nf * 16 + ll;
#pragma unroll
      for (int kk = 0; kk < 2; kk++) {
        int vc = (kk * 4 + lg) ^ (d & 7);
        bf16x8 vb = *(const bf16x8*)((const char*)&Vt[buf][0] + d * 128 + vc * 16);
        oacc[nf] = __builtin_amdgcn_mfma_f32_16x16x32_bf16(vb, pb[kk], oacc[nf], 0, 0, 0);
      }
    }
    if (has_next) {
      unsigned int* vt32 = (unsigned int*)&Vt[buf ^ 1][0];
#pragma unroll
      for (int i = 0; i < 8; i++)
        vt32[(dg * 8 + i) * 32 + (((kp >> 2) ^ i) << 2) + (kp & 3)] =
            (unsigned int)n0.s[i] | ((unsigned int)n1.s[i] << 16);
    }
    __syncthreads();
    buf ^= 1;
  }

  float rl = 1.0f / lrun;
#pragma unroll
  for (int nf = 0; nf < 4; nf++) {
    ushort4 ov;
    ov.x = f2bf(oacc[nf][0] * rl);
    ov.y = f2bf(oacc[nf][1] * rl);
    ov.z = f2bf(oacc[nf][2] * rl);
    ov.w = f2bf(oacc[nf][3] * rl);
    *(ushort4*)(attn_o + (size_t)(b * SEQ + q_lane) * D_MODEL + h * 64 + nf * 16 + lg * 4) = ov;
  }
}

// ------------------------------------------------------------------------------
extern "C" void kernel_launch(void* const* d_in, const int* in_sizes, int n_in,
                              void* d_out, int out_size, void* d_ws, size_t ws_size,
                              hipStream_t stream) {
  const float* hidden_states = (const float*)d_in[0];
  const float* temb     = (const float*)d_in[2];
  const float* rope_cos = (const float*)d_in[3];
  const float* rope_sin = (const float*)d_in[4];
  const float* ln1_w    = (const float*)d_in[5];
  const float* ln1_b    = (const float*)d_in[6];
  const float* ln2_w    = (const float*)d_in[7];
  const float* ln2_b    = (const float*)d_in[8];
  const float* c_attn_w = (const float*)d_in[9];
  const float* c_attn_b = (const float*)d_in[10];
  const float* c_proj_w = (const float*)d_in[11];
  const float* c_proj_b = (const float*)d_in[12];
  const float* fc_w     = (const float*)d_in[13];
  const float* fc_b     = (const float*)d_in[14];
  const float* proj_w   = (const float*)d_in[15];
  const float* proj_b   = (const float*)d_in[16];
  const float* sst      = (const float*)d_in[17];

  char* ws = (char*)d_ws;
  unsigned short* wqkv  = (unsigned short*)(ws + 0);          // 6.29MB
  unsigned short* wproj = (unsigned short*)(ws + 6291456);    // 2.10MB
  unsigned short* wfc   = (unsigned short*)(ws + 8388608);    // 8.39MB
  unsigned short* wp2   = (unsigned short*)(ws + 16777216);   // 8.39MB (live in final)
  unsigned short* hln   = (unsigned short*)(ws + 25165824);   // 8.39MB
  unsigned short* qkvb  = (unsigned short*)(ws + 33554432);   // 25.2MB
  unsigned short* attno = (unsigned short*)(ws + 58720256);   // 8.39MB
  unsigned short* hiddenb = (unsigned short*)(ws + 67108864); // 8.39MB bf16 residual
  unsigned short* rp0 = (unsigned short*)(ws + 33554432);     // alias dead qkvb
  unsigned short* rp1 = (unsigned short*)(ws + 41943040);
  unsigned short* h3  = (unsigned short*)(ws + 33554432);     // 33.5MB (live in final)
  unsigned short* fp0 = (unsigned short*)(ws + 0);            // dead wqkv/wproj
  unsigned short* fp1 = (unsigned short*)(ws + 8388608);      // dead wfc

  // prologue: weight transposes + LN1 modulation (independent, one launch)
  prologue_kernel<<<16384, 256, 0, stream>>>(
      c_attn_w, c_proj_w, fc_w, proj_w, wqkv, wproj, wfc, wp2,
      hidden_states, ln1_w, ln1_b, sst, temb, hln);

  // qkv: 2-phase, NK=16 -> 768 blocks
  gemm64<EPI_QKV, 16><<<dim3(3072 / 128, ROWS / 128, 1), 256, 0, stream>>>(
      hln, wqkv, c_attn_b, qkvb, qkvb, 3072, 1024, rope_cos, rope_sin);

  attn_kernel<<<dim3(32 * 32), 256, 0, stream>>>(qkvb, attno);

  // attn proj: 2-phase split-K=2 (NK=8) + fused reduce+LN2 (bf16 residual out)
  gemm64<EPI_PART, 8><<<dim3(1024 / 128, ROWS / 128, 2), 256, 0, stream>>>(
      attno, wproj, c_proj_b, rp0, rp1, 1024, 1024, nullptr, nullptr);
  reduce_ln<<<ROWS, 256, 0, stream>>>(
      rp0, rp1, c_proj_b, sst, temb, hidden_states, hiddenb, ln2_w, ln2_b, hln);

  // fc+gelu: 2-phase, NK=16 -> 1024 blocks
  gemm64<EPI_GELU, 16><<<dim3(4096 / 128, ROWS / 128, 1), 256, 0, stream>>>(
      hln, wfc, fc_b, h3, h3, 4096, 1024, nullptr, nullptr);

  // mlp proj: 2-phase split-K=2 (NK=32 each) + gated reduce (bf16 residual in)
  gemm64<EPI_PART, 32><<<dim3(1024 / 128, ROWS / 128, 2), 256, 0, stream>>>(
      h3, wp2, proj_b, fp0, fp1, 1024, 4096, nullptr, nullptr);
  reduce_gated<<<(ROWS * D_MODEL / 4) / 256, 256, 0, stream>>>(
      fp0, fp1, proj_b, sst, temb, 5, hiddenb, (float*)d_out);
}